// Round 5
// baseline (1574.762 us; speedup 1.0000x reference)
//
#include <hip/hip_runtime.h>

// Laplacian pyramid build: im (16,3,1024,1024) fp32, levels=5. P = 48 planes.
// SINGLE persistent kernel (normal launch, graph-safe), 5 phases separated by a
// software grid barrier (monotonic counter in d_ws, device-scope atomics):
//   P1: reduce0 (im -> s1)
//   P2: lap0 (im,s1 -> s0, NT)  +  reduce1 (s1 -> s2)
//   P3: lap1 (s1,s2 -> s1)      +  reduce2 (s2 -> s3)
//   P4: lap2 (s2,s3 -> s2)      +  reduce3 (s3 -> s4)
//   P5: lap3 (s3,s4 -> s3)
// Grid = 1024 blocks; __launch_bounds__(256,4) caps VGPR at 128 so 4 blocks/CU
// are schedulable -> all 1024 co-resident on 256 CUs. Bounded spin (~0.5 s)
// turns any residency failure into a visible correctness fail, never a hang.
// Fallback (ws too small): R3's proven 5-dispatch plan.

typedef float fx4 __attribute__((ext_vector_type(4)));  // native vec for NT builtins

// ---------------- reduce: 5x5 binomial, stride 2, edge clamp ----------------
// Register-blocked, LDS-free. Each thread computes a 4x4 output tile.
template <bool EDGE>
__device__ __forceinline__ void reduce_accum(const float* __restrict__ src,
                                             int Hin, int Win, int rbase, int cb,
                                             float (&acc)[4][4]) {
    const float w0 = 0.0625f, w1 = 0.25f, w2 = 0.375f;
    const float wr[5] = {w0, w1, w2, w1, w0};
#pragma unroll
    for (int rr = 0; rr < 11; ++rr) {
        int gr = rbase + rr;
        gr = gr < 0 ? 0 : (gr > Hin - 1 ? Hin - 1 : gr);
        const float* row = src + (size_t)gr * Win;
        float v[16];
        if (!EDGE) {
#pragma unroll
            for (int q = 0; q < 4; ++q) {
                fx4 f = *reinterpret_cast<const fx4*>(row + cb + 4 * q);
                v[4 * q + 0] = f.x; v[4 * q + 1] = f.y;
                v[4 * q + 2] = f.z; v[4 * q + 3] = f.w;
            }
        } else {
#pragma unroll
            for (int c = 0; c < 16; ++c) {
                int gc = cb + c;
                gc = gc < 0 ? 0 : (gc > Win - 1 ? Win - 1 : gc);
                v[c] = row[gc];
            }
        }
        float h[4];
#pragma unroll
        for (int c = 0; c < 4; ++c) {
            const float* vv = v + 2 + 2 * c;
            float s04 = vv[0] + vv[4];
            float s13 = vv[1] + vv[3];
            float hh = w0 * s04;
            hh = fmaf(w1, s13, hh);
            hh = fmaf(w2, vv[2], hh);
            h[c] = hh;
        }
#pragma unroll
        for (int i = 0; i < 4; ++i) {
            const int a = rr - 2 * i;
            if (a >= 0 && a <= 4) {
                const float w = wr[a];
#pragma unroll
                for (int c = 0; c < 4; ++c)
                    acc[i][c] = fmaf(w, h[c], acc[i][c]);
            }
        }
    }
}

__device__ __forceinline__ void reduce_block(const float* __restrict__ src,
                                             float* __restrict__ dst,
                                             int Hin, int Win, int Hout, int Wout,
                                             int bx, int by, int tx, int ty) {
    const int t = bx * 64 + tx;           // output col group: j0 = 4t
    const int i0 = (by * 4 + ty) * 4;     // first output row
    const int j0 = 4 * t;
    if (j0 >= Wout || i0 >= Hout) return;

    const int cb = 8 * t - 4;        // first loaded input col (16B aligned)
    const int rbase = 2 * i0 - 2;    // first needed input row
    const bool edge = (cb < 0) | (cb + 15 > Win - 1);

    float acc[4][4];
#pragma unroll
    for (int i = 0; i < 4; ++i)
#pragma unroll
        for (int c = 0; c < 4; ++c) acc[i][c] = 0.f;

    if (!edge) reduce_accum<false>(src, Hin, Win, rbase, cb, acc);
    else       reduce_accum<true>(src, Hin, Win, rbase, cb, acc);

    float* drow = dst + j0;
#pragma unroll
    for (int i = 0; i < 4; ++i) {
        fx4 o = {acc[i][0], acc[i][1], acc[i][2], acc[i][3]};
        *reinterpret_cast<fx4*>(drow + (size_t)(i0 + i) * Wout) = o;
    }
}

// ------------- lap: lpyr[l] = fine - expand(coarse) -------------
// 4 coarse cols / thread -> fine cols 8t..8t+7, rows 2i,2i+1 (16 outputs).
template <bool NT>
__device__ __forceinline__ fx4 ld4(const float* p) {
    if (NT) return __builtin_nontemporal_load(reinterpret_cast<const fx4*>(p));
    return *reinterpret_cast<const fx4*>(p);
}
template <bool NT>
__device__ __forceinline__ void st4(float* p, fx4 v) {
    if (NT) __builtin_nontemporal_store(v, reinterpret_cast<fx4*>(p));
    else    *reinterpret_cast<fx4*>(p) = v;
}

template <bool NT>
__device__ __forceinline__ void lap_block(const float* __restrict__ fine,
                                          const float* __restrict__ coarse,
                                          float* __restrict__ out,
                                          int Hc, int Wc, int bx, int by, int tx, int ty) {
    const int t = bx * 64 + tx;      // coarse col quad: cols 4t..4t+3
    const int i = by * 4 + ty;       // coarse row
    if (i >= Hc || t >= (Wc >> 2)) return;

    const int im1 = i > 0 ? i - 1 : 0;
    const int ip1 = i < Hc - 1 ? i + 1 : Hc - 1;
    const float* rm = coarse + (size_t)im1 * Wc;
    const float* r0 = coarse + (size_t)i   * Wc;
    const float* rp = coarse + (size_t)ip1 * Wc;

    const int jl = 4 * t - 1 > 0 ? 4 * t - 1 : 0;             // clamp(4t-1)
    const int jr = 4 * t + 4 < Wc - 1 ? 4 * t + 4 : Wc - 1;   // clamp(4t+4)

    // coarse cols 4t-1 .. 4t+4 for three rows
    float cm[6], c0[6], cp[6];
    {
        fx4 m = *reinterpret_cast<const fx4*>(rm + 4 * t);
        fx4 z = *reinterpret_cast<const fx4*>(r0 + 4 * t);
        fx4 q = *reinterpret_cast<const fx4*>(rp + 4 * t);
        cm[1] = m.x; cm[2] = m.y; cm[3] = m.z; cm[4] = m.w;
        c0[1] = z.x; c0[2] = z.y; c0[3] = z.z; c0[4] = z.w;
        cp[1] = q.x; cp[2] = q.y; cp[3] = q.z; cp[4] = q.w;
        cm[0] = rm[jl]; cm[5] = rm[jr];
        c0[0] = r0[jl]; c0[5] = r0[jr];
        cp[0] = rp[jl]; cp[5] = rp[jr];
    }

    // vertical combine
    float e[6], o[6];
#pragma unroll
    for (int c = 0; c < 6; ++c) {
        e[c] = fmaf(0.125f, cm[c], fmaf(0.75f, c0[c], 0.125f * cp[c]));
        o[c] = 0.5f * (c0[c] + cp[c]);
    }

    // horizontal combine: fine cols 8t..8t+7 (e[1] == coarse col 4t)
    float ev[8], ov[8];
#pragma unroll
    for (int q = 0; q < 4; ++q) {
        ev[2 * q]     = fmaf(0.125f, e[q], fmaf(0.75f, e[q + 1], 0.125f * e[q + 2]));
        ev[2 * q + 1] = 0.5f * (e[q + 1] + e[q + 2]);
        ov[2 * q]     = fmaf(0.125f, o[q], fmaf(0.75f, o[q + 1], 0.125f * o[q + 2]));
        ov[2 * q + 1] = 0.5f * (o[q + 1] + o[q + 2]);
    }

    const int Wf = 2 * Wc;
    const size_t r0off = (size_t)(2 * i) * Wf + 8 * t;
    const float* f0 = fine + r0off;
    const float* f1 = f0 + Wf;
    fx4 a0 = ld4<NT>(f0), a1 = ld4<NT>(f0 + 4);
    fx4 b0 = ld4<NT>(f1), b1 = ld4<NT>(f1 + 4);

    float* w0 = out + r0off;
    float* w1 = w0 + Wf;
    fx4 o0 = {a0.x - ev[0], a0.y - ev[1], a0.z - ev[2], a0.w - ev[3]};
    fx4 o1 = {a1.x - ev[4], a1.y - ev[5], a1.z - ev[6], a1.w - ev[7]};
    fx4 o2 = {b0.x - ov[0], b0.y - ov[1], b0.z - ov[2], b0.w - ov[3]};
    fx4 o3 = {b1.x - ov[4], b1.y - ov[5], b1.z - ov[6], b1.w - ov[7]};
    st4<NT>(w0,     o0);
    st4<NT>(w0 + 4, o1);
    st4<NT>(w1,     o2);
    st4<NT>(w1 + 4, o3);
}

// ---------------- software grid barrier ----------------
// Monotonic counter: barrier k complete when ctr >= nblk*k. Induction: a block
// can only arrive at barrier k+1 after ctr >= nblk*k, so the first time ctr
// reaches nblk*k, all nblk blocks have arrived at barrier k.
__device__ __forceinline__ void gbar(unsigned* ctr, unsigned target) {
    __syncthreads();
    if (threadIdx.x == 0 && threadIdx.y == 0) {
        __threadfence();  // release: our phase-k stores visible device-wide
        __hip_atomic_fetch_add(ctr, 1u, __ATOMIC_ACQ_REL, __HIP_MEMORY_SCOPE_AGENT);
        unsigned spins = 0;
        while (__hip_atomic_load(ctr, __ATOMIC_ACQUIRE, __HIP_MEMORY_SCOPE_AGENT) < target) {
            __builtin_amdgcn_s_sleep(8);
            if (++spins > 2000000u) break;   // failsafe: fail visibly, never hang
        }
        __threadfence();  // acquire: other blocks' stores visible to us
    }
    __syncthreads();
}

// ---------------- persistent mega-kernel ----------------
// Slice offsets (floats): s0=0, s1, s2, s3, s4.
#define OFF1 50331648UL   // 48*1024*1024
#define OFF2 62914560UL   // + 48*512*512
#define OFF3 66060288UL   // + 48*256*256
#define OFF4 66846720UL   // + 48*128*128

__launch_bounds__(256, 4)
__global__ void pyr_kernel(const float* __restrict__ im, float* __restrict__ out,
                           unsigned* ctr) {
    const int tx = threadIdx.x, ty = threadIdx.y;
    const unsigned gsz = gridDim.x;
    const unsigned nblk = gsz;

    // Phase 1: reduce0 im -> s1 (1024 -> 512). 2x32 tiles/plane = 64, 3072 total.
    for (unsigned bt = blockIdx.x; bt < 3072; bt += gsz) {
        unsigned p = bt >> 6, r = bt & 63;
        reduce_block(im + (size_t)p * (1024 * 1024), out + OFF1 + (size_t)p * (512 * 512),
                     1024, 1024, 512, 512, r & 1, r >> 1, tx, ty);
    }
    gbar(ctr, nblk * 1);

    // Phase 2: lap0 (2x128/plane = 256 -> 12288 tiles) + reduce1 (16/plane -> 768).
    for (unsigned bt = blockIdx.x; bt < 13056; bt += gsz) {
        if (bt < 12288) {
            unsigned p = bt >> 8, r = bt & 255;
            lap_block<true>(im + (size_t)p * (1024 * 1024),
                            out + OFF1 + (size_t)p * (512 * 512),
                            out + (size_t)p * (1024 * 1024),
                            512, 512, r & 1, r >> 1, tx, ty);
        } else {
            unsigned b2 = bt - 12288;
            unsigned p = b2 >> 4, r = b2 & 15;
            reduce_block(out + OFF1 + (size_t)p * (512 * 512), out + OFF2 + (size_t)p * (256 * 256),
                         512, 512, 256, 256, 0, r, tx, ty);
        }
    }
    gbar(ctr, nblk * 2);

    // Phase 3: lap1 (64/plane -> 3072) + reduce2 (8/plane -> 384).
    for (unsigned bt = blockIdx.x; bt < 3456; bt += gsz) {
        if (bt < 3072) {
            unsigned p = bt >> 6, by = bt & 63;
            lap_block<false>(out + OFF1 + (size_t)p * (512 * 512),
                             out + OFF2 + (size_t)p * (256 * 256),
                             out + OFF1 + (size_t)p * (512 * 512),
                             256, 256, 0, by, tx, ty);
        } else {
            unsigned b2 = bt - 3072;
            unsigned p = b2 >> 3, r = b2 & 7;
            reduce_block(out + OFF2 + (size_t)p * (256 * 256), out + OFF3 + (size_t)p * (128 * 128),
                         256, 256, 128, 128, 0, r, tx, ty);
        }
    }
    gbar(ctr, nblk * 3);

    // Phase 4: lap2 (32/plane -> 1536) + reduce3 (4/plane -> 192).
    for (unsigned bt = blockIdx.x; bt < 1728; bt += gsz) {
        if (bt < 1536) {
            unsigned p = bt >> 5, by = bt & 31;
            lap_block<false>(out + OFF2 + (size_t)p * (256 * 256),
                             out + OFF3 + (size_t)p * (128 * 128),
                             out + OFF2 + (size_t)p * (256 * 256),
                             128, 128, 0, by, tx, ty);
        } else {
            unsigned b2 = bt - 1536;
            unsigned p = b2 >> 2, r = b2 & 3;
            reduce_block(out + OFF3 + (size_t)p * (128 * 128), out + OFF4 + (size_t)p * (64 * 64),
                         128, 128, 64, 64, 0, r, tx, ty);
        }
    }
    gbar(ctr, nblk * 4);

    // Phase 5: lap3 (16/plane -> 768).
    for (unsigned bt = blockIdx.x; bt < 768; bt += gsz) {
        unsigned p = bt >> 4, by = bt & 15;
        lap_block<false>(out + OFF3 + (size_t)p * (128 * 128),
                         out + OFF4 + (size_t)p * (64 * 64),
                         out + OFF3 + (size_t)p * (128 * 128),
                         64, 64, 0, by, tx, ty);
    }
}

// ---------------- fallback kernels (R3's proven 5-dispatch plan) ----------------
__launch_bounds__(256)
__global__ void reduce_kernel(const float* __restrict__ in, float* __restrict__ out,
                              int Hin, int Win, int Hout, int Wout) {
    const int p = blockIdx.z;
    reduce_block(in + (size_t)p * Hin * Win, out + (size_t)p * Hout * Wout,
                 Hin, Win, Hout, Wout, blockIdx.x, blockIdx.y, threadIdx.x, threadIdx.y);
}

__launch_bounds__(256)
__global__ void lap_kernel(const float* __restrict__ fine, const float* __restrict__ coarse,
                           float* __restrict__ out, int Hc, int Wc) {
    const int p = blockIdx.z;
    const size_t mplane = (size_t)Hc * Wc;
    lap_block<false>(fine + (size_t)p * 4 * mplane, coarse + (size_t)p * mplane,
                     out + (size_t)p * 4 * mplane, Hc, Wc,
                     blockIdx.x, blockIdx.y, threadIdx.x, threadIdx.y);
}

template <bool NT>
__launch_bounds__(256)
__global__ void fused_kernel(const float* __restrict__ fine, const float* __restrict__ mid,
                             float* __restrict__ lap_dst, float* __restrict__ red_dst,
                             int Hc, int Wc, int ylap) {
    const int p = blockIdx.z;
    const size_t mplane = (size_t)Hc * Wc;
    if ((int)blockIdx.y < ylap) {
        lap_block<NT>(fine + (size_t)p * 4 * mplane, mid + (size_t)p * mplane,
                      lap_dst + (size_t)p * 4 * mplane, Hc, Wc,
                      blockIdx.x, blockIdx.y, threadIdx.x, threadIdx.y);
    } else {
        reduce_block(mid + (size_t)p * mplane, red_dst + (size_t)p * (mplane >> 2),
                     Hc, Wc, Hc >> 1, Wc >> 1,
                     blockIdx.x, (int)blockIdx.y - ylap, threadIdx.x, threadIdx.y);
    }
}

extern "C" void kernel_launch(void* const* d_in, const int* in_sizes, int n_in,
                              void* d_out, int out_size, void* d_ws, size_t ws_size,
                              hipStream_t stream) {
    (void)in_sizes; (void)n_in; (void)out_size;
    const float* im = (const float*)d_in[0];
    float* out = (float*)d_out;

    if (d_ws != nullptr && ws_size >= 64) {
        // Persistent single-kernel path.
        hipMemsetAsync(d_ws, 0, 64, stream);
        unsigned* ctr = (unsigned*)d_ws;
        pyr_kernel<<<dim3(1024, 1, 1), dim3(64, 4, 1), 0, stream>>>(im, out, ctr);
        return;
    }

    // Fallback: 5-dispatch plan (R3).
    const int P = 48;
    const int H0 = 1024, W0 = 1024;
    size_t off[5];
    size_t acc = 0;
    for (int l = 0; l < 5; ++l) {
        off[l] = acc;
        int h = H0 >> l, w = W0 >> l;
        acc += (size_t)P * h * w;
    }
    {
        int Hout = H0 >> 1, Wout = W0 >> 1;
        dim3 blk(64, 4, 1);
        dim3 grid((Wout + 255) / 256, (Hout + 15) / 16, P);
        reduce_kernel<<<grid, blk, 0, stream>>>(im, out + off[1], H0, W0, Hout, Wout);
    }
    for (int l = 0; l < 3; ++l) {
        int Hc = H0 >> (l + 1), Wc = W0 >> (l + 1);
        int xlap = (Wc / 4 + 63) / 64, ylap = (Hc + 3) / 4;
        int Hout = Hc >> 1, Wout = Wc >> 1;
        int xred = (Wout + 255) / 256, yred = (Hout + 15) / 16;
        dim3 blk(64, 4, 1);
        dim3 grid(xlap > xred ? xlap : xred, ylap + yred, P);
        const float* fine = (l == 0) ? im : (out + off[l]);
        if (l == 0)
            fused_kernel<true><<<grid, blk, 0, stream>>>(fine, out + off[l + 1],
                                                         out + off[l], out + off[l + 2],
                                                         Hc, Wc, ylap);
        else
            fused_kernel<false><<<grid, blk, 0, stream>>>(fine, out + off[l + 1],
                                                          out + off[l], out + off[l + 2],
                                                          Hc, Wc, ylap);
    }
    {
        int Hc = H0 >> 4, Wc = W0 >> 4;
        dim3 blk(64, 4, 1);
        dim3 grid((Wc / 4 + 63) / 64, (Hc + 3) / 4, P);
        lap_kernel<<<grid, blk, 0, stream>>>(out + off[3], out + off[4], out + off[3], Hc, Wc);
    }
}